// Round 12
// baseline (325.280 us; speedup 1.0000x reference)
//
#include <hip/hip_runtime.h>
#include <hip/hip_bf16.h>

typedef __attribute__((ext_vector_type(8))) short short8;
typedef __attribute__((ext_vector_type(4))) float f32x4;

__device__ inline f32x4 mfma16(short8 a, short8 b, f32x4 c) {
    return __builtin_amdgcn_mfma_f32_16x16x32_bf16(a, b, c, 0, 0, 0);
}
__device__ inline short f2bf(float x) {
    __hip_bfloat16 h = __float2bfloat16(x);
    return *reinterpret_cast<short*>(&h);
}
__device__ inline unsigned short f2bfu(float x) {
    __hip_bfloat16 h = __float2bfloat16(x);
    return *reinterpret_cast<unsigned short*>(&h);
}
__device__ inline float bf2f(short u) {
    __hip_bfloat16 h = *reinterpret_cast<__hip_bfloat16*>(&u);
    return __bfloat162float(h);
}
// native packed f32x2 -> bf16x2 (lo=a, hi=b). Inline asm per T12; RNE.
__device__ inline unsigned int cvt_pk_bf16(float a, float b) {
    unsigned int r;
    asm("v_cvt_pk_bf16_f32 %0, %1, %2" : "=v"(r) : "v"(a), "v"(b));
    return r;
}
__device__ inline float scrub(float v, float s) {
    return (fabsf(v) < 1e30f) ? v : s;
}
__device__ inline short8 scaleq(short8 v) {   // fold 1/sqrt(hd)=0.125 into Q (exact in bf16)
    short8 r;
#pragma unroll
    for (int j = 0; j < 8; j++) r[j] = f2bf(bf2f(v[j]) * 0.125f);
    return r;
}

// ---- dtype detection ----
__global__ void detect_dtype(const unsigned short* __restrict__ x, int* flag) {
    __shared__ int cnt;
    if (threadIdx.x == 0) cnt = 0;
    __syncthreads();
    int c = 0;
    for (int i = threadIdx.x; i < 1024; i += 256) {
        unsigned short u = x[i];
        int e = (u >> 7) & 0xFF;
        if ((u & 0x7FFF) == 0 || (e >= 110 && e <= 143)) c++;
    }
    atomicAdd(&cnt, c);
    __syncthreads();
    if (threadIdx.x == 0) flag[0] = (cnt < 819) ? 1 : 0;
}

__global__ void conv_bias(const void* __restrict__ in, short* __restrict__ out,
                          int n, const int* __restrict__ flag) {
    int i = blockIdx.x * 256 + threadIdx.x;
    if (i >= n) return;
    out[i] = (*flag) ? f2bf(((const float*)in)[i]) : ((const short*)in)[i];
}

__global__ __launch_bounds__(256) void conv_x(const void* __restrict__ in,
                                              short* __restrict__ out, int n,
                                              const int* __restrict__ flag) {
    int i = (blockIdx.x * 256 + threadIdx.x) * 4;
    if (i >= n) return;
    if (*flag) {
        float4 f = *(const float4*)((const float*)in + i);
        *(uint2*)(out + i) = make_uint2(cvt_pk_bf16(f.x, f.y), cvt_pk_bf16(f.z, f.w));
    } else {
        *(uint2*)(out + i) = *(const uint2*)((const short*)in + i);
    }
}

__global__ void fill_sentinel(void* out, int n, const int* __restrict__ flag) {
    int i = blockIdx.x * 256 + threadIdx.x;
    if (i >= n) return;
    if (*flag) ((float*)out)[i] = 3e5f; else ((short*)out)[i] = f2bf(3e5f);
}

// ---- transpose (poly input) ----
__global__ __launch_bounds__(256) void transpose_poly(const void* __restrict__ in,
                                                      short* __restrict__ out,
                                                      int R, int C,
                                                      const int* __restrict__ flag) {
    __shared__ short tile[32][33];
    const bool f32 = (*flag) != 0;
    int tx = threadIdx.x & 31, ty = threadIdx.x >> 5;
    int r0 = blockIdx.y * 32, c0 = blockIdx.x * 32;
#pragma unroll
    for (int i = 0; i < 4; i++) {
        size_t off = (size_t)(r0 + ty + i * 8) * C + c0 + tx;
        tile[ty + i * 8][tx] = f32 ? f2bf(((const float*)in)[off]) : ((const short*)in)[off];
    }
    __syncthreads();
#pragma unroll
    for (int i = 0; i < 4; i++)
        out[(size_t)(c0 + ty + i * 8) * R + r0 + tx] = tile[tx][ty + i * 8];
}

// ---- GEMM 128x128: R9 register-prefetch pipeline (both gemms) ---------------
#define LDK 72

__global__ __launch_bounds__(256) void gemm_bt(const short* __restrict__ A,
                                               const short* __restrict__ Bt,
                                               const short* __restrict__ bias,
                                               void* __restrict__ Cv,
                                               int N, int K,
                                               const int* __restrict__ flag,
                                               int c_poly, float sent) {
    alignas(16) __shared__ short As[128 * LDK];
    alignas(16) __shared__ short Bs[128 * LDK];
    const bool cf32 = c_poly && (*flag);
    int tid = threadIdx.x;
    int wave = tid >> 6, lane = tid & 63;
    int lrow = lane & 15, lq = lane >> 4;
    int wm = (wave >> 1) * 64, wn = (wave & 1) * 64;
    int m0 = blockIdx.y * 128, n0 = blockIdx.x * 128;

    f32x4 acc[4][4];
#pragma unroll
    for (int i = 0; i < 4; i++)
#pragma unroll
        for (int j = 0; j < 4; j++) acc[i][j] = (f32x4){0.f, 0.f, 0.f, 0.f};

    int srow = tid >> 3;
    int scol = (tid & 7) * 8;

    short8 ar[4], br[4];
#pragma unroll
    for (int p = 0; p < 4; p++) {
        int row = p * 32 + srow;
        ar[p] = *(const short8*)&A[(size_t)(m0 + row) * K + scol];
        br[p] = *(const short8*)&Bt[(size_t)(n0 + row) * K + scol];
    }

    for (int kb = 0; kb < K; kb += 64) {
#pragma unroll
        for (int p = 0; p < 4; p++) {
            int row = p * 32 + srow;
            *(short8*)&As[row * LDK + scol] = ar[p];
            *(short8*)&Bs[row * LDK + scol] = br[p];
        }
        __syncthreads();

        int kn = (kb + 64 < K) ? kb + 64 : kb;
#pragma unroll
        for (int p = 0; p < 4; p++) {
            int row = p * 32 + srow;
            ar[p] = *(const short8*)&A[(size_t)(m0 + row) * K + kn + scol];
            br[p] = *(const short8*)&Bt[(size_t)(n0 + row) * K + kn + scol];
        }

#pragma unroll
        for (int ks = 0; ks < 2; ks++) {
            short8 af[4], bf[4];
#pragma unroll
            for (int i = 0; i < 4; i++)
                af[i] = *(short8*)&As[(wm + i * 16 + lrow) * LDK + ks * 32 + lq * 8];
#pragma unroll
            for (int i = 0; i < 4; i++)
                bf[i] = *(short8*)&Bs[(wn + i * 16 + lrow) * LDK + ks * 32 + lq * 8];
#pragma unroll
            for (int i = 0; i < 4; i++)
#pragma unroll
                for (int j = 0; j < 4; j++)
                    acc[i][j] = mfma16(af[i], bf[j], acc[i][j]);
        }
        __syncthreads();
    }

    const __hip_bfloat16* bias16 = (const __hip_bfloat16*)bias;
#pragma unroll
    for (int j = 0; j < 4; j++) {
        int col = n0 + wn + j * 16 + lrow;
        float bv = __bfloat162float(bias16[col]);
#pragma unroll
        for (int i = 0; i < 4; i++) {
            int rbase = m0 + wm + i * 16 + lq * 4;
#pragma unroll
            for (int r = 0; r < 4; r++) {
                float val = scrub(acc[i][j][r] + bv, sent);
                size_t off = (size_t)(rbase + r) * N + col;
                if (cf32) ((float*)Cv)[off] = val; else ((short*)Cv)[off] = f2bf(val);
            }
        }
    }
}

// ---- flash attention: R11 body + cross-block KV-SPLIT ----------------------
// R10/R11 proved attn is latency-bound at 2 blocks/CU (grid 512) and neither
// VALU cuts nor softmax-chain cuts move it. This round doubles the grid with
// the SAME 4-wave body: blockIdx.x = bx*2 + spl; block (bx, spl) runs both
// tiles of the pair (bx*128, 1920-bx*128) over kv-units u = spl, spl+2, ...
// -> 17 units/block causal (bx+1 + 16-bx), 32 dense: uniform by construction,
// no dispatch assumption. 1024 blocks -> 4 blocks/CU (LDS 4x36,864 <= 160K,
// VGPR 104 -> 16 waves/CU).
// Fixed-max (R11) makes partials ADDITIVE: each block writes its own
// l-normalized O_s (bf16; the pre-normalization makes bf16-l quantization
// cancel to first order in the merge) + per-row l_s (bf16, ws slack).
// s=0 -> d_out (scratch until final gemm), s=1 -> xbfAO. attn_merge combines:
// O = (O0*l0 + O1*l1)/(l0+l1). Zero-coverage rows (causal, spl=1, q<64):
// l=0 exactly, O_s = NaN -> scrub -> finite, weight 0 -> exact. Poison still
// terminates in sentinels (inf l -> NaN weights -> final-gemm scrub).
#define VP2 72
#define PP 72
#define MFIX 8.0f

__global__ __launch_bounds__(256, 2) void attn_kernel(const short* __restrict__ QKV,
                                                      short* __restrict__ P0,
                                                      short* __restrict__ P1,
                                                      unsigned short* __restrict__ lbuf,
                                                      const int* __restrict__ maskp) {
    constexpr int S = 2048, C3 = 3072;
    alignas(16) __shared__ short Vt[2][64 * VP2];
    alignas(16) __shared__ short Pt[4][2][16 * PP];

    int tid = threadIdx.x;
    int wave = tid >> 6, lane = tid & 63;
    int lrow = lane & 15, lq = lane >> 4;
    int bx = blockIdx.x >> 1, spl = blockIdx.x & 1;
    int bh = blockIdx.y;
    const bool causal = (*maskp) != 0;
    const short* base = QKV + (size_t)(bh >> 4) * S * C3 + (bh & 15) * 192;

    int vi2 = (tid & 31) * 2;     // kv pair base for V staging
    int vd0 = (tid >> 5) * 8;     // 8 d per thread

    int buf = 0;
    for (int tile = 0; tile < 2; tile++) {
        int q0t = (tile == 0) ? bx * 128 : 1920 - bx * 128;

        int qg[2];
        short8 qf0[2], qf1[2];
#pragma unroll
        for (int g = 0; g < 2; g++) {
            qg[g] = q0t + wave * 32 + g * 16 + lrow;
            qf0[g] = scaleq(*(const short8*)(base + (size_t)qg[g] * C3 + lq * 8));
            qf1[g] = scaleq(*(const short8*)(base + (size_t)qg[g] * C3 + 32 + lq * 8));
        }

        float l_i[2] = {0.f, 0.f};          // per-lane partial row sums
        f32x4 acc[2][4];
#pragma unroll
        for (int g = 0; g < 2; g++)
#pragma unroll
            for (int nt = 0; nt < 4; nt++) acc[g][nt] = (f32x4){0.f, 0.f, 0.f, 0.f};

        int nunits = (causal ? (q0t + 128) : S) >> 6;   // even; >= 2

        // ---- prologue: prefetch V + K for unit u = spl into registers ----
        short8 va, vb, kf0[4], kf1[4];
        {
            int kv0p = spl << 6;
            const short* vs0 = base + (size_t)(kv0p + vi2) * C3 + 128 + vd0;
            va = *(const short8*)vs0;
            vb = *(const short8*)(vs0 + C3);
#pragma unroll
            for (int sub = 0; sub < 4; sub++) {
                const short* kb = base + (size_t)(kv0p + sub * 16 + lrow) * C3 + 64;
                kf0[sub] = *(const short8*)(kb + lq * 8);
                kf1[sub] = *(const short8*)(kb + 32 + lq * 8);
            }
        }

        for (int u = spl; u < nunits; u += 2) {
            int kv0 = u << 6;
            // ---- write pre-staged V^T (64 kv x 64 d) into LDS ----
            {
                union { short8 v; unsigned short uu[8]; } a, b;
                a.v = va; b.v = vb;
                unsigned int* vt = (unsigned int*)&Vt[buf][0];
#pragma unroll
                for (int j = 0; j < 8; j++)
                    vt[((vd0 + j) * VP2 + vi2) >> 1] =
                        ((unsigned int)b.uu[j] << 16) | a.uu[j];
            }
            __syncthreads();

            // ---- issue next-unit global loads early (clamped on last) ----
            int un = (u + 2 < nunits) ? u + 2 : u;
            int kvn = un << 6;
            short8 va_n, vb_n, kf0_n[4], kf1_n[4];
            {
                const short* vs0 = base + (size_t)(kvn + vi2) * C3 + 128 + vd0;
                va_n = *(const short8*)vs0;
                vb_n = *(const short8*)(vs0 + C3);
#pragma unroll
                for (int sub = 0; sub < 4; sub++) {
                    const short* kb = base + (size_t)(kvn + sub * 16 + lrow) * C3 + 64;
                    kf0_n[sub] = *(const short8*)(kb + lq * 8);
                    kf1_n[sub] = *(const short8*)(kb + 32 + lq * 8);
                }
            }

            // ---- S^T for both groups using pre-loaded K ----
            f32x4 s[2][4];
#pragma unroll
            for (int sub = 0; sub < 4; sub++) {
#pragma unroll
                for (int g = 0; g < 2; g++) {
                    f32x4 a = (f32x4){0.f, 0.f, 0.f, 0.f};
                    a = mfma16(kf0[sub], qf0[g], a);
                    a = mfma16(kf1[sub], qf1[g], a);
                    s[g][sub] = a;
                }
            }

            // ---- per-group: mask, fixed-max exp, pack P ----
#pragma unroll
            for (int g = 0; g < 2; g++) {
                if (causal && (kv0 + 63 > q0t + wave * 32 + g * 16)) {
#pragma unroll
                    for (int sub = 0; sub < 4; sub++) {
                        int kvg = kv0 + sub * 16 + lq * 4;
#pragma unroll
                        for (int rr = 0; rr < 4; rr++)
                            if (kvg + rr > qg[g]) s[g][sub][rr] = -1e30f;
                    }
                }
                float lsum = 0.f;
                unsigned int pk[4][2];
#pragma unroll
                for (int sub = 0; sub < 4; sub++) {
                    float p0 = __expf(s[g][sub][0] - MFIX);
                    float p1 = __expf(s[g][sub][1] - MFIX);
                    float p2 = __expf(s[g][sub][2] - MFIX);
                    float p3 = __expf(s[g][sub][3] - MFIX);
                    lsum += (p0 + p1) + (p2 + p3);
                    pk[sub][0] = cvt_pk_bf16(p0, p1);
                    pk[sub][1] = cvt_pk_bf16(p2, p3);
                }
                l_i[g] += lsum;              // per-lane; reduced in epilogue
                unsigned int* pt = (unsigned int*)&Pt[wave][g][0];
#pragma unroll
                for (int sub = 0; sub < 4; sub++)
                    *(uint2*)&pt[(lrow * PP + sub * 16 + lq * 4) >> 1] =
                        make_uint2(pk[sub][0], pk[sub][1]);
            }

            // ---- PV: O^T += V^T · P^T, vf shared across groups ----
#pragma unroll
            for (int ks = 0; ks < 2; ks++) {
                short8 pfA = *(short8*)&Pt[wave][0][lrow * PP + ks * 32 + lq * 8];
                short8 pfB = *(short8*)&Pt[wave][1][lrow * PP + ks * 32 + lq * 8];
#pragma unroll
                for (int nt = 0; nt < 4; nt++) {
                    short8 vf = *(short8*)&Vt[buf][(nt * 16 + lrow) * VP2 + ks * 32 + lq * 8];
                    acc[0][nt] = mfma16(vf, pfA, acc[0][nt]);
                    acc[1][nt] = mfma16(vf, pfB, acc[1][nt]);
                }
            }

            // ---- rotate prefetched registers ----
            va = va_n; vb = vb_n;
#pragma unroll
            for (int sub = 0; sub < 4; sub++) {
                kf0[sub] = kf0_n[sub];
                kf1[sub] = kf1_n[sub];
            }
            buf ^= 1;
        }

        // ---- epilogue: reduce partial row-sum, self-normalize, write ----
        short* Pd = spl ? P1 : P0;
#pragma unroll
        for (int g = 0; g < 2; g++) {
            float lt = l_i[g];
            lt += __shfl_xor(lt, 16, 64);
            lt += __shfl_xor(lt, 32, 64);
            float inv = 1.f / lt;            // lt==0 -> inf -> NaN -> scrub
            short* ob = Pd + ((size_t)bh * S + qg[g]) * 64;
#pragma unroll
            for (int nt = 0; nt < 4; nt++) {
                float o0 = scrub(acc[g][nt][0] * inv, 4e4f);
                float o1 = scrub(acc[g][nt][1] * inv, 4e4f);
                float o2 = scrub(acc[g][nt][2] * inv, 4e4f);
                float o3 = scrub(acc[g][nt][3] * inv, 4e4f);
                *(uint2*)(ob + nt * 16 + lq * 4) =
                    make_uint2(cvt_pk_bf16(o0, o1), cvt_pk_bf16(o2, o3));
            }
            if (lq == 0)
                lbuf[spl * (64 * 2048) + bh * 2048 + qg[g]] = f2bfu(lt);
        }
    }
}

// ---- merge the two kv-split partials: O = (O0*l0 + O1*l1)/(l0+l1) ----------
__global__ __launch_bounds__(256) void attn_merge(const short* __restrict__ P0,
                                                  short* __restrict__ P1,
                                                  const unsigned short* __restrict__ lbuf) {
    size_t i = ((size_t)blockIdx.x * 256 + threadIdx.x) * 4;
    int row = (int)(i >> 6);                 // bh*2048 + q
    float l0 = bf2f((short)lbuf[row]);
    float l1 = bf2f((short)lbuf[64 * 2048 + row]);
    float inv = 1.f / (l0 + l1);
    float w0 = l0 * inv, w1 = l1 * inv;
    uint2 a = *(const uint2*)(P0 + i);
    uint2 b = *(const uint2*)(P1 + i);
    float o0 = w0 * bf2f((short)(a.x & 0xFFFF)) + w1 * bf2f((short)(b.x & 0xFFFF));
    float o1 = w0 * bf2f((short)(a.x >> 16))    + w1 * bf2f((short)(b.x >> 16));
    float o2 = w0 * bf2f((short)(a.y & 0xFFFF)) + w1 * bf2f((short)(b.y & 0xFFFF));
    float o3 = w0 * bf2f((short)(a.y >> 16))    + w1 * bf2f((short)(b.y >> 16));
    *(uint2*)(P1 + i) = make_uint2(cvt_pk_bf16(o0, o1), cvt_pk_bf16(o2, o3));
}

// ---- launch ----
extern "C" void kernel_launch(void* const* d_in, const int* in_sizes, int n_in,
                              void* d_out, int out_size, void* d_ws, size_t ws_size,
                              hipStream_t stream) {
    char* ws = (char*)d_ws;
    int*   flag  = (int*)ws;
    short* bq_bf = (short*)(ws + 65536);
    short* bo_bf = (short*)(ws + 131072);
    unsigned short* lbuf = (unsigned short*)(ws + 196608);  // 512 KB, ends < 1 MiB
    short* WqkvT = (short*)(ws + (1ull << 20));
    short* WoutT = (short*)(ws + 7ull * (1ull << 20));
    short* xbfAO = (short*)(ws + 9ull * (1ull << 20));   // x_bf, later AO / s=1 partial
    short* QKVc  = (short*)(ws + 25ull * (1ull << 20));

    detect_dtype<<<1, 256, 0, stream>>>((const unsigned short*)d_in[0], flag);

    if (ws_size < 73ull * 1048576) {
        fill_sentinel<<<(8388608 + 255) / 256, 256, 0, stream>>>(d_out, 8388608, flag);
        return;
    }

    conv_bias<<<12, 256, 0, stream>>>(d_in[2], bq_bf, 3072, flag);
    conv_bias<<<4, 256, 0, stream>>>(d_in[4], bo_bf, 1024, flag);
    transpose_poly<<<dim3(96, 32), 256, 0, stream>>>(d_in[1], WqkvT, 1024, 3072, flag);
    transpose_poly<<<dim3(32, 32), 256, 0, stream>>>(d_in[3], WoutT, 1024, 1024, flag);
    conv_x<<<8192, 256, 0, stream>>>(d_in[0], xbfAO, 8388608, flag);

    gemm_bt<<<dim3(24, 64), 256, 0, stream>>>(xbfAO, WqkvT, bq_bf, QKVc,
                                              3072, 1024, flag, 0, 8e4f);
    // kv-split attn: s=0 partial -> d_out (scratch), s=1 partial -> xbfAO
    attn_kernel<<<dim3(16, 64), 256, 0, stream>>>(QKVc, (short*)d_out, xbfAO,
                                                  lbuf, (const int*)d_in[5]);
    attn_merge<<<8192, 256, 0, stream>>>((const short*)d_out, xbfAO, lbuf);
    gemm_bt<<<dim3(8, 64), 256, 0, stream>>>(xbfAO, WoutT, bo_bf, d_out,
                                             1024, 1024, flag, 1, 2e4f);
}

// Round 13
// 306.381 us; speedup vs baseline: 1.0617x; 1.0617x over previous
//
#include <hip/hip_runtime.h>
#include <hip/hip_bf16.h>

typedef __attribute__((ext_vector_type(8))) short short8;
typedef __attribute__((ext_vector_type(4))) float f32x4;

__device__ inline f32x4 mfma16(short8 a, short8 b, f32x4 c) {
    return __builtin_amdgcn_mfma_f32_16x16x32_bf16(a, b, c, 0, 0, 0);
}
__device__ inline short f2bf(float x) {
    __hip_bfloat16 h = __float2bfloat16(x);
    return *reinterpret_cast<short*>(&h);
}
__device__ inline unsigned short f2bfu(float x) {
    __hip_bfloat16 h = __float2bfloat16(x);
    return *reinterpret_cast<unsigned short*>(&h);
}
__device__ inline float bf2f(short u) {
    __hip_bfloat16 h = *reinterpret_cast<__hip_bfloat16*>(&u);
    return __bfloat162float(h);
}
// native packed f32x2 -> bf16x2 (lo=a, hi=b). Inline asm per T12; RNE.
__device__ inline unsigned int cvt_pk_bf16(float a, float b) {
    unsigned int r;
    asm("v_cvt_pk_bf16_f32 %0, %1, %2" : "=v"(r) : "v"(a), "v"(b));
    return r;
}
__device__ inline float scrub(float v, float s) {
    return (fabsf(v) < 1e30f) ? v : s;
}
__device__ inline short8 scaleq(short8 v) {   // fold 1/sqrt(hd)=0.125 into Q (exact in bf16)
    short8 r;
#pragma unroll
    for (int j = 0; j < 8; j++) r[j] = f2bf(bf2f(v[j]) * 0.125f);
    return r;
}

// ---- dtype detection ----
__global__ void detect_dtype(const unsigned short* __restrict__ x, int* flag) {
    __shared__ int cnt;
    if (threadIdx.x == 0) cnt = 0;
    __syncthreads();
    int c = 0;
    for (int i = threadIdx.x; i < 1024; i += 256) {
        unsigned short u = x[i];
        int e = (u >> 7) & 0xFF;
        if ((u & 0x7FFF) == 0 || (e >= 110 && e <= 143)) c++;
    }
    atomicAdd(&cnt, c);
    __syncthreads();
    if (threadIdx.x == 0) flag[0] = (cnt < 819) ? 1 : 0;
}

__global__ void conv_bias(const void* __restrict__ in, short* __restrict__ out,
                          int n, const int* __restrict__ flag) {
    int i = blockIdx.x * 256 + threadIdx.x;
    if (i >= n) return;
    out[i] = (*flag) ? f2bf(((const float*)in)[i]) : ((const short*)in)[i];
}

__global__ __launch_bounds__(256) void conv_x(const void* __restrict__ in,
                                              short* __restrict__ out, int n,
                                              const int* __restrict__ flag) {
    int i = (blockIdx.x * 256 + threadIdx.x) * 4;
    if (i >= n) return;
    if (*flag) {
        float4 f = *(const float4*)((const float*)in + i);
        *(uint2*)(out + i) = make_uint2(cvt_pk_bf16(f.x, f.y), cvt_pk_bf16(f.z, f.w));
    } else {
        *(uint2*)(out + i) = *(const uint2*)((const short*)in + i);
    }
}

__global__ void fill_sentinel(void* out, int n, const int* __restrict__ flag) {
    int i = blockIdx.x * 256 + threadIdx.x;
    if (i >= n) return;
    if (*flag) ((float*)out)[i] = 3e5f; else ((short*)out)[i] = f2bf(3e5f);
}

// ---- transpose (poly input) ----
__global__ __launch_bounds__(256) void transpose_poly(const void* __restrict__ in,
                                                      short* __restrict__ out,
                                                      int R, int C,
                                                      const int* __restrict__ flag) {
    __shared__ short tile[32][33];
    const bool f32 = (*flag) != 0;
    int tx = threadIdx.x & 31, ty = threadIdx.x >> 5;
    int r0 = blockIdx.y * 32, c0 = blockIdx.x * 32;
#pragma unroll
    for (int i = 0; i < 4; i++) {
        size_t off = (size_t)(r0 + ty + i * 8) * C + c0 + tx;
        tile[ty + i * 8][tx] = f32 ? f2bf(((const float*)in)[off]) : ((const short*)in)[off];
    }
    __syncthreads();
#pragma unroll
    for (int i = 0; i < 4; i++)
        out[(size_t)(c0 + ty + i * 8) * R + r0 + tx] = tile[tx][ty + i * 8];
}

// ---- GEMM 128x128: R9 pipeline + T1 XCD-chunked block swizzle ---------------
// Default round-robin block->XCD spreads the blocks sharing an A-panel over
// all 8 XCD L2s (~8x A re-fetch). Chunked swizzle: XCD k executes work items
// [k*nwg/8, (k+1)*nwg/8) -> 8 contiguous m-rows per XCD (2 MB of A-panels,
// L2-resident). Bijective: both grids (1536, 512) are %8 == 0.
#define LDK 72

__global__ __launch_bounds__(256) void gemm_bt(const short* __restrict__ A,
                                               const short* __restrict__ Bt,
                                               const short* __restrict__ bias,
                                               void* __restrict__ Cv,
                                               int N, int K,
                                               const int* __restrict__ flag,
                                               int c_poly, float sent) {
    alignas(16) __shared__ short As[128 * LDK];
    alignas(16) __shared__ short Bs[128 * LDK];
    const bool cf32 = c_poly && (*flag);
    int tid = threadIdx.x;
    int wave = tid >> 6, lane = tid & 63;
    int lrow = lane & 15, lq = lane >> 4;
    int wm = (wave >> 1) * 64, wn = (wave & 1) * 64;

    // XCD-chunked swizzle (T1)
    int id = blockIdx.x + gridDim.x * blockIdx.y;
    int q8 = (gridDim.x * gridDim.y) >> 3;
    int swz = (id & 7) * q8 + (id >> 3);
    int m0 = (swz / gridDim.x) * 128;
    int n0 = (swz % gridDim.x) * 128;

    f32x4 acc[4][4];
#pragma unroll
    for (int i = 0; i < 4; i++)
#pragma unroll
        for (int j = 0; j < 4; j++) acc[i][j] = (f32x4){0.f, 0.f, 0.f, 0.f};

    int srow = tid >> 3;
    int scol = (tid & 7) * 8;

    short8 ar[4], br[4];
#pragma unroll
    for (int p = 0; p < 4; p++) {
        int row = p * 32 + srow;
        ar[p] = *(const short8*)&A[(size_t)(m0 + row) * K + scol];
        br[p] = *(const short8*)&Bt[(size_t)(n0 + row) * K + scol];
    }

    for (int kb = 0; kb < K; kb += 64) {
#pragma unroll
        for (int p = 0; p < 4; p++) {
            int row = p * 32 + srow;
            *(short8*)&As[row * LDK + scol] = ar[p];
            *(short8*)&Bs[row * LDK + scol] = br[p];
        }
        __syncthreads();

        int kn = (kb + 64 < K) ? kb + 64 : kb;
#pragma unroll
        for (int p = 0; p < 4; p++) {
            int row = p * 32 + srow;
            ar[p] = *(const short8*)&A[(size_t)(m0 + row) * K + kn + scol];
            br[p] = *(const short8*)&Bt[(size_t)(n0 + row) * K + kn + scol];
        }

#pragma unroll
        for (int ks = 0; ks < 2; ks++) {
            short8 af[4], bf[4];
#pragma unroll
            for (int i = 0; i < 4; i++)
                af[i] = *(short8*)&As[(wm + i * 16 + lrow) * LDK + ks * 32 + lq * 8];
#pragma unroll
            for (int i = 0; i < 4; i++)
                bf[i] = *(short8*)&Bs[(wn + i * 16 + lrow) * LDK + ks * 32 + lq * 8];
#pragma unroll
            for (int i = 0; i < 4; i++)
#pragma unroll
                for (int j = 0; j < 4; j++)
                    acc[i][j] = mfma16(af[i], bf[j], acc[i][j]);
        }
        __syncthreads();
    }

    const __hip_bfloat16* bias16 = (const __hip_bfloat16*)bias;
#pragma unroll
    for (int j = 0; j < 4; j++) {
        int col = n0 + wn + j * 16 + lrow;
        float bv = __bfloat162float(bias16[col]);
#pragma unroll
        for (int i = 0; i < 4; i++) {
            int rbase = m0 + wm + i * 16 + lq * 4;
#pragma unroll
            for (int r = 0; r < 4; r++) {
                float val = scrub(acc[i][j][r] + bv, sent);
                size_t off = (size_t)(rbase + r) * N + col;
                if (cf32) ((float*)Cv)[off] = val; else ((short*)Cv)[off] = f2bf(val);
            }
        }
    }
}

// ---- flash attention: R11 body + DEFERRED PV (T15 analog) ------------------
// R12 disproved the TLP path conclusively: occupancy is pinned at ~21% by the
// hardware regardless of grid/LDS/VGPR (R0/R6/R12 all ~21-23%), and per-CU
// time is ~constant per kv-unit. Only ILP has ever helped (R7: -19us).
// This round removes the remaining exposed serial segment: exp -> cvt ->
// P ds_write -> lgkmcnt -> P ds_read -> PV. PV is DEFERRED one unit: iter u
// runs {barrier; stage V(u)->buf; prefetch(u+1); QK(u); PV(u-1) reading
// Vt[buf^1] + Pt(written last iter); softmax(u) -> Pt}. The P write->read
// distance becomes a full unit, and PV-MFMA overlaps softmax-VALU.
// Race analysis: stage(u) writes buf, PV(u-1) reads buf^1 (disjoint); next
// write to buf^1 is stage(u+1), behind barrier(u+1), reached only after all
// waves' PV(u-1) -- safe. Pt read-then-write is same-wave same-address,
// order-preserved. Epilogue PV(last) needs one __syncthreads() (cross-wave
// staging visibility). Fixed-max (R11) kept: no running max, l reduced once.
#define VP2 72
#define PP 72
#define MFIX 8.0f

__global__ __launch_bounds__(256, 2) void attn_kernel(const short* __restrict__ QKV,
                                                      short* __restrict__ AO,
                                                      const int* __restrict__ maskp) {
    constexpr int S = 2048, C3 = 3072;
    alignas(16) __shared__ short Vt[2][64 * VP2];
    alignas(16) __shared__ short Pt[4][2][16 * PP];

    int tid = threadIdx.x;
    int wave = tid >> 6, lane = tid & 63;
    int lrow = lane & 15, lq = lane >> 4;
    int bh = blockIdx.y;
    const bool causal = (*maskp) != 0;
    const short* base = QKV + (size_t)(bh >> 4) * S * C3 + (bh & 15) * 192;

    int vi2 = (tid & 31) * 2;     // kv pair base for V staging
    int vd0 = (tid >> 5) * 8;     // 8 d per thread

    int buf = 0;
    for (int tile = 0; tile < 2; tile++) {
        int q0t = (tile == 0) ? blockIdx.x * 128 : 1920 - blockIdx.x * 128;

        int qg[2];
        short8 qf0[2], qf1[2];
#pragma unroll
        for (int g = 0; g < 2; g++) {
            qg[g] = q0t + wave * 32 + g * 16 + lrow;
            qf0[g] = scaleq(*(const short8*)(base + (size_t)qg[g] * C3 + lq * 8));
            qf1[g] = scaleq(*(const short8*)(base + (size_t)qg[g] * C3 + 32 + lq * 8));
        }

        float l_i[2] = {0.f, 0.f};          // per-lane partial row sums
        f32x4 acc[2][4];
#pragma unroll
        for (int g = 0; g < 2; g++)
#pragma unroll
            for (int nt = 0; nt < 4; nt++) acc[g][nt] = (f32x4){0.f, 0.f, 0.f, 0.f};

        int nkv = causal ? (q0t + 128) : S;

        // ---- prologue: prefetch V + K for kv0 = 0 into registers ----
        short8 va, vb, kf0[4], kf1[4];
        {
            const short* vs0 = base + (size_t)vi2 * C3 + 128 + vd0;
            va = *(const short8*)vs0;
            vb = *(const short8*)(vs0 + C3);
#pragma unroll
            for (int sub = 0; sub < 4; sub++) {
                const short* kb = base + (size_t)(sub * 16 + lrow) * C3 + 64;
                kf0[sub] = *(const short8*)(kb + lq * 8);
                kf1[sub] = *(const short8*)(kb + 32 + lq * 8);
            }
        }

        for (int kv0 = 0; kv0 < nkv; kv0 += 64) {
            // ---- barrier FIRST: Vt[buf] free (last readers: PV(u-2)) ----
            __syncthreads();

            // ---- write pre-staged V^T (64 kv x 64 d) into Vt[buf] ----
            {
                union { short8 v; unsigned short u[8]; } a, b;
                a.v = va; b.v = vb;
                unsigned int* vt = (unsigned int*)&Vt[buf][0];
#pragma unroll
                for (int j = 0; j < 8; j++)
                    vt[((vd0 + j) * VP2 + vi2) >> 1] =
                        ((unsigned int)b.u[j] << 16) | a.u[j];
            }

            // ---- issue next-iter global loads early (clamped on last) ----
            int kvn = (kv0 + 64 < nkv) ? kv0 + 64 : kv0;
            short8 va_n, vb_n, kf0_n[4], kf1_n[4];
            {
                const short* vs0 = base + (size_t)(kvn + vi2) * C3 + 128 + vd0;
                va_n = *(const short8*)vs0;
                vb_n = *(const short8*)(vs0 + C3);
#pragma unroll
                for (int sub = 0; sub < 4; sub++) {
                    const short* kb = base + (size_t)(kvn + sub * 16 + lrow) * C3 + 64;
                    kf0_n[sub] = *(const short8*)(kb + lq * 8);
                    kf1_n[sub] = *(const short8*)(kb + 32 + lq * 8);
                }
            }

            // ---- QK(u): S^T for both groups using pre-loaded K ----
            f32x4 s[2][4];
#pragma unroll
            for (int sub = 0; sub < 4; sub++) {
#pragma unroll
                for (int g = 0; g < 2; g++) {
                    f32x4 a = (f32x4){0.f, 0.f, 0.f, 0.f};
                    a = mfma16(kf0[sub], qf0[g], a);
                    a = mfma16(kf1[sub], qf1[g], a);
                    s[g][sub] = a;
                }
            }

            // ---- PV(u-1): Vt[buf^1] staged last iter, Pt written last iter --
            if (kv0 > 0) {
#pragma unroll
                for (int ks = 0; ks < 2; ks++) {
                    short8 pfA = *(short8*)&Pt[wave][0][lrow * PP + ks * 32 + lq * 8];
                    short8 pfB = *(short8*)&Pt[wave][1][lrow * PP + ks * 32 + lq * 8];
#pragma unroll
                    for (int nt = 0; nt < 4; nt++) {
                        short8 vf = *(short8*)&Vt[buf ^ 1][(nt * 16 + lrow) * VP2 + ks * 32 + lq * 8];
                        acc[0][nt] = mfma16(vf, pfA, acc[0][nt]);
                        acc[1][nt] = mfma16(vf, pfB, acc[1][nt]);
                    }
                }
            }

            // ---- softmax(u): mask, fixed-max exp, pack P -> Pt ----
#pragma unroll
            for (int g = 0; g < 2; g++) {
                if (causal && (kv0 + 63 > q0t + wave * 32 + g * 16)) {
#pragma unroll
                    for (int sub = 0; sub < 4; sub++) {
                        int kvg = kv0 + sub * 16 + lq * 4;
#pragma unroll
                        for (int rr = 0; rr < 4; rr++)
                            if (kvg + rr > qg[g]) s[g][sub][rr] = -1e30f;
                    }
                }
                float lsum = 0.f;
                unsigned int pk[4][2];
#pragma unroll
                for (int sub = 0; sub < 4; sub++) {
                    float p0 = __expf(s[g][sub][0] - MFIX);
                    float p1 = __expf(s[g][sub][1] - MFIX);
                    float p2 = __expf(s[g][sub][2] - MFIX);
                    float p3 = __expf(s[g][sub][3] - MFIX);
                    lsum += (p0 + p1) + (p2 + p3);
                    pk[sub][0] = cvt_pk_bf16(p0, p1);
                    pk[sub][1] = cvt_pk_bf16(p2, p3);
                }
                l_i[g] += lsum;              // per-lane; reduced in epilogue
                unsigned int* pt = (unsigned int*)&Pt[wave][g][0];
#pragma unroll
                for (int sub = 0; sub < 4; sub++)
                    *(uint2*)&pt[(lrow * PP + sub * 16 + lq * 4) >> 1] =
                        make_uint2(pk[sub][0], pk[sub][1]);
            }

            // ---- rotate prefetched registers ----
            va = va_n; vb = vb_n;
#pragma unroll
            for (int sub = 0; sub < 4; sub++) {
                kf0[sub] = kf0_n[sub];
                kf1[sub] = kf1_n[sub];
            }
            buf ^= 1;
        }

        // ---- drain: PV(last). Barrier makes ALL waves' staging of the ----
        // ---- final V-tile (in Vt[buf^1]) visible.                      ----
        __syncthreads();
#pragma unroll
        for (int ks = 0; ks < 2; ks++) {
            short8 pfA = *(short8*)&Pt[wave][0][lrow * PP + ks * 32 + lq * 8];
            short8 pfB = *(short8*)&Pt[wave][1][lrow * PP + ks * 32 + lq * 8];
#pragma unroll
            for (int nt = 0; nt < 4; nt++) {
                short8 vf = *(short8*)&Vt[buf ^ 1][(nt * 16 + lrow) * VP2 + ks * 32 + lq * 8];
                acc[0][nt] = mfma16(vf, pfA, acc[0][nt]);
                acc[1][nt] = mfma16(vf, pfB, acc[1][nt]);
            }
        }

        // ---- epilogue: reduce row-sum across lq once, normalize, pack ----
#pragma unroll
        for (int g = 0; g < 2; g++) {
            float lt = l_i[g];
            lt += __shfl_xor(lt, 16, 64);
            lt += __shfl_xor(lt, 32, 64);
            float inv = 1.f / lt;
            short* ob = AO + ((size_t)bh * S + qg[g]) * 64;
#pragma unroll
            for (int nt = 0; nt < 4; nt++) {
                float o0 = scrub(acc[g][nt][0] * inv, 4e4f);
                float o1 = scrub(acc[g][nt][1] * inv, 4e4f);
                float o2 = scrub(acc[g][nt][2] * inv, 4e4f);
                float o3 = scrub(acc[g][nt][3] * inv, 4e4f);
                *(uint2*)(ob + nt * 16 + lq * 4) =
                    make_uint2(cvt_pk_bf16(o0, o1), cvt_pk_bf16(o2, o3));
            }
        }
    }
}

// ---- launch ----
extern "C" void kernel_launch(void* const* d_in, const int* in_sizes, int n_in,
                              void* d_out, int out_size, void* d_ws, size_t ws_size,
                              hipStream_t stream) {
    char* ws = (char*)d_ws;
    int*   flag  = (int*)ws;
    short* bq_bf = (short*)(ws + 65536);
    short* bo_bf = (short*)(ws + 131072);
    short* WqkvT = (short*)(ws + (1ull << 20));
    short* WoutT = (short*)(ws + 7ull * (1ull << 20));
    short* xbfAO = (short*)(ws + 9ull * (1ull << 20));   // x_bf, later AO
    short* QKVc  = (short*)(ws + 25ull * (1ull << 20));

    detect_dtype<<<1, 256, 0, stream>>>((const unsigned short*)d_in[0], flag);

    if (ws_size < 73ull * 1048576) {
        fill_sentinel<<<(8388608 + 255) / 256, 256, 0, stream>>>(d_out, 8388608, flag);
        return;
    }

    conv_bias<<<12, 256, 0, stream>>>(d_in[2], bq_bf, 3072, flag);
    conv_bias<<<4, 256, 0, stream>>>(d_in[4], bo_bf, 1024, flag);
    transpose_poly<<<dim3(96, 32), 256, 0, stream>>>(d_in[1], WqkvT, 1024, 3072, flag);
    transpose_poly<<<dim3(32, 32), 256, 0, stream>>>(d_in[3], WoutT, 1024, 1024, flag);
    conv_x<<<8192, 256, 0, stream>>>(d_in[0], xbfAO, 8388608, flag);

    gemm_bt<<<dim3(24, 64), 256, 0, stream>>>(xbfAO, WqkvT, bq_bf, QKVc,
                                              3072, 1024, flag, 0, 8e4f);
    attn_kernel<<<dim3(8, 64), 256, 0, stream>>>(QKVc, xbfAO, (const int*)d_in[5]);
    gemm_bt<<<dim3(8, 64), 256, 0, stream>>>(xbfAO, WoutT, bo_bf, d_out,
                                             1024, 1024, flag, 1, 2e4f);
}

// Round 14
// 303.489 us; speedup vs baseline: 1.0718x; 1.0095x over previous
//
#include <hip/hip_runtime.h>
#include <hip/hip_bf16.h>

typedef __attribute__((ext_vector_type(8))) short short8;
typedef __attribute__((ext_vector_type(4))) float f32x4;

__device__ inline f32x4 mfma16(short8 a, short8 b, f32x4 c) {
    return __builtin_amdgcn_mfma_f32_16x16x32_bf16(a, b, c, 0, 0, 0);
}
__device__ inline short f2bf(float x) {
    __hip_bfloat16 h = __float2bfloat16(x);
    return *reinterpret_cast<short*>(&h);
}
__device__ inline unsigned short f2bfu(float x) {
    __hip_bfloat16 h = __float2bfloat16(x);
    return *reinterpret_cast<unsigned short*>(&h);
}
__device__ inline float bf2f(short u) {
    __hip_bfloat16 h = *reinterpret_cast<__hip_bfloat16*>(&u);
    return __bfloat162float(h);
}
// native packed f32x2 -> bf16x2 (lo=a, hi=b). Inline asm per T12; RNE.
__device__ inline unsigned int cvt_pk_bf16(float a, float b) {
    unsigned int r;
    asm("v_cvt_pk_bf16_f32 %0, %1, %2" : "=v"(r) : "v"(a), "v"(b));
    return r;
}
__device__ inline float scrub(float v, float s) {
    return (fabsf(v) < 1e30f) ? v : s;
}
__device__ inline short8 scaleq(short8 v) {   // fold 1/sqrt(hd)=0.125 into Q (exact in bf16)
    short8 r;
#pragma unroll
    for (int j = 0; j < 8; j++) r[j] = f2bf(bf2f(v[j]) * 0.125f);
    return r;
}

// ---- dtype detection ----
__global__ void detect_dtype(const unsigned short* __restrict__ x, int* flag) {
    __shared__ int cnt;
    if (threadIdx.x == 0) cnt = 0;
    __syncthreads();
    int c = 0;
    for (int i = threadIdx.x; i < 1024; i += 256) {
        unsigned short u = x[i];
        int e = (u >> 7) & 0xFF;
        if ((u & 0x7FFF) == 0 || (e >= 110 && e <= 143)) c++;
    }
    atomicAdd(&cnt, c);
    __syncthreads();
    if (threadIdx.x == 0) flag[0] = (cnt < 819) ? 1 : 0;
}

__global__ void conv_bias(const void* __restrict__ in, short* __restrict__ out,
                          int n, const int* __restrict__ flag) {
    int i = blockIdx.x * 256 + threadIdx.x;
    if (i >= n) return;
    out[i] = (*flag) ? f2bf(((const float*)in)[i]) : ((const short*)in)[i];
}

__global__ __launch_bounds__(256) void conv_x(const void* __restrict__ in,
                                              short* __restrict__ out, int n,
                                              const int* __restrict__ flag) {
    int i = (blockIdx.x * 256 + threadIdx.x) * 4;
    if (i >= n) return;
    if (*flag) {
        float4 f = *(const float4*)((const float*)in + i);
        *(uint2*)(out + i) = make_uint2(cvt_pk_bf16(f.x, f.y), cvt_pk_bf16(f.z, f.w));
    } else {
        *(uint2*)(out + i) = *(const uint2*)((const short*)in + i);
    }
}

__global__ void fill_sentinel(void* out, int n, const int* __restrict__ flag) {
    int i = blockIdx.x * 256 + threadIdx.x;
    if (i >= n) return;
    if (*flag) ((float*)out)[i] = 3e5f; else ((short*)out)[i] = f2bf(3e5f);
}

// ---- transpose (poly input) ----
__global__ __launch_bounds__(256) void transpose_poly(const void* __restrict__ in,
                                                      short* __restrict__ out,
                                                      int R, int C,
                                                      const int* __restrict__ flag) {
    __shared__ short tile[32][33];
    const bool f32 = (*flag) != 0;
    int tx = threadIdx.x & 31, ty = threadIdx.x >> 5;
    int r0 = blockIdx.y * 32, c0 = blockIdx.x * 32;
#pragma unroll
    for (int i = 0; i < 4; i++) {
        size_t off = (size_t)(r0 + ty + i * 8) * C + c0 + tx;
        tile[ty + i * 8][tx] = f32 ? f2bf(((const float*)in)[off]) : ((const short*)in)[off];
    }
    __syncthreads();
#pragma unroll
    for (int i = 0; i < 4; i++)
        out[(size_t)(c0 + ty + i * 8) * R + r0 + tx] = tile[tx][ty + i * 8];
}

// ---- GEMM 128x128: R9 register-prefetch pipeline (swizzle REVERTED) ---------
// R13 lesson: XCD-chunked swizzle cost +3.6 us on the gemms -- the weights
// are L3-resident anyway and the remap broke the default co-scheduling of
// same-m blocks. Plain blockIdx mapping restored (R9-identical).
#define LDK 72

__global__ __launch_bounds__(256) void gemm_bt(const short* __restrict__ A,
                                               const short* __restrict__ Bt,
                                               const short* __restrict__ bias,
                                               void* __restrict__ Cv,
                                               int N, int K,
                                               const int* __restrict__ flag,
                                               int c_poly, float sent) {
    alignas(16) __shared__ short As[128 * LDK];
    alignas(16) __shared__ short Bs[128 * LDK];
    const bool cf32 = c_poly && (*flag);
    int tid = threadIdx.x;
    int wave = tid >> 6, lane = tid & 63;
    int lrow = lane & 15, lq = lane >> 4;
    int wm = (wave >> 1) * 64, wn = (wave & 1) * 64;
    int m0 = blockIdx.y * 128, n0 = blockIdx.x * 128;

    f32x4 acc[4][4];
#pragma unroll
    for (int i = 0; i < 4; i++)
#pragma unroll
        for (int j = 0; j < 4; j++) acc[i][j] = (f32x4){0.f, 0.f, 0.f, 0.f};

    int srow = tid >> 3;
    int scol = (tid & 7) * 8;

    short8 ar[4], br[4];
#pragma unroll
    for (int p = 0; p < 4; p++) {
        int row = p * 32 + srow;
        ar[p] = *(const short8*)&A[(size_t)(m0 + row) * K + scol];
        br[p] = *(const short8*)&Bt[(size_t)(n0 + row) * K + scol];
    }

    for (int kb = 0; kb < K; kb += 64) {
#pragma unroll
        for (int p = 0; p < 4; p++) {
            int row = p * 32 + srow;
            *(short8*)&As[row * LDK + scol] = ar[p];
            *(short8*)&Bs[row * LDK + scol] = br[p];
        }
        __syncthreads();

        int kn = (kb + 64 < K) ? kb + 64 : kb;
#pragma unroll
        for (int p = 0; p < 4; p++) {
            int row = p * 32 + srow;
            ar[p] = *(const short8*)&A[(size_t)(m0 + row) * K + kn + scol];
            br[p] = *(const short8*)&Bt[(size_t)(n0 + row) * K + kn + scol];
        }

#pragma unroll
        for (int ks = 0; ks < 2; ks++) {
            short8 af[4], bf[4];
#pragma unroll
            for (int i = 0; i < 4; i++)
                af[i] = *(short8*)&As[(wm + i * 16 + lrow) * LDK + ks * 32 + lq * 8];
#pragma unroll
            for (int i = 0; i < 4; i++)
                bf[i] = *(short8*)&Bs[(wn + i * 16 + lrow) * LDK + ks * 32 + lq * 8];
#pragma unroll
            for (int i = 0; i < 4; i++)
#pragma unroll
                for (int j = 0; j < 4; j++)
                    acc[i][j] = mfma16(af[i], bf[j], acc[i][j]);
        }
        __syncthreads();
    }

    const __hip_bfloat16* bias16 = (const __hip_bfloat16*)bias;
#pragma unroll
    for (int j = 0; j < 4; j++) {
        int col = n0 + wn + j * 16 + lrow;
        float bv = __bfloat162float(bias16[col]);
#pragma unroll
        for (int i = 0; i < 4; i++) {
            int rbase = m0 + wm + i * 16 + lq * 4;
#pragma unroll
            for (int r = 0; r < 4; r++) {
                float val = scrub(acc[i][j][r] + bv, sent);
                size_t off = (size_t)(rbase + r) * N + col;
                if (cf32) ((float*)Cv)[off] = val; else ((short*)Cv)[off] = f2bf(val);
            }
        }
    }
}

// ---- flash attention: R13 deferred-PV body + HEAD->XCD affinity swizzle ----
// R13 ledger: 99 us / 68 units-per-CU = ~3500 cy/unit vs ~800 cy MFMA+VALU
// -> ~2700 cy still exposed. Prefetch distance (~1000 cy) covers L2 (~200)
// but not L3 (~400-600). K/V for one bh (512 KB) is read by the 8 blocks
// bh*8+bx -- which round-robin dispatch spreads over all 8 XCD L2s, so every
// XCD re-fetches from L3. Remap (T1, reuse-directed): hardware linear id
// h = bx + 8*by; xcd = h&7; j = h>>3; bh = (h&7) + 8*(j&7); bx = j>>3 --
// bijective over 8x64, and ALL 8 blocks of a head land on ONE XCD. K/V then
// lives in that XCD's L2 (~2-4 heads x 512 KB << 4 MB) -> prefetch distance
// covers the L2 hit. Pure index remap: correctness unaffected if the XCD
// dispatch model is wrong (it only costs locality).
#define VP2 72
#define PP 72
#define MFIX 8.0f

__global__ __launch_bounds__(256, 2) void attn_kernel(const short* __restrict__ QKV,
                                                      short* __restrict__ AO,
                                                      const int* __restrict__ maskp) {
    constexpr int S = 2048, C3 = 3072;
    alignas(16) __shared__ short Vt[2][64 * VP2];
    alignas(16) __shared__ short Pt[4][2][16 * PP];

    int tid = threadIdx.x;
    int wave = tid >> 6, lane = tid & 63;
    int lrow = lane & 15, lq = lane >> 4;

    // head->XCD affinity decode
    int h = blockIdx.x + (blockIdx.y << 3);
    int j = h >> 3;
    int bh = (h & 7) + ((j & 7) << 3);
    int bx = j >> 3;

    const bool causal = (*maskp) != 0;
    const short* base = QKV + (size_t)(bh >> 4) * S * C3 + (bh & 15) * 192;

    int vi2 = (tid & 31) * 2;     // kv pair base for V staging
    int vd0 = (tid >> 5) * 8;     // 8 d per thread

    int buf = 0;
    for (int tile = 0; tile < 2; tile++) {
        int q0t = (tile == 0) ? bx * 128 : 1920 - bx * 128;

        int qg[2];
        short8 qf0[2], qf1[2];
#pragma unroll
        for (int g = 0; g < 2; g++) {
            qg[g] = q0t + wave * 32 + g * 16 + lrow;
            qf0[g] = scaleq(*(const short8*)(base + (size_t)qg[g] * C3 + lq * 8));
            qf1[g] = scaleq(*(const short8*)(base + (size_t)qg[g] * C3 + 32 + lq * 8));
        }

        float l_i[2] = {0.f, 0.f};          // per-lane partial row sums
        f32x4 acc[2][4];
#pragma unroll
        for (int g = 0; g < 2; g++)
#pragma unroll
            for (int nt = 0; nt < 4; nt++) acc[g][nt] = (f32x4){0.f, 0.f, 0.f, 0.f};

        int nkv = causal ? (q0t + 128) : S;

        // ---- prologue: prefetch V + K for kv0 = 0 into registers ----
        short8 va, vb, kf0[4], kf1[4];
        {
            const short* vs0 = base + (size_t)vi2 * C3 + 128 + vd0;
            va = *(const short8*)vs0;
            vb = *(const short8*)(vs0 + C3);
#pragma unroll
            for (int sub = 0; sub < 4; sub++) {
                const short* kb = base + (size_t)(sub * 16 + lrow) * C3 + 64;
                kf0[sub] = *(const short8*)(kb + lq * 8);
                kf1[sub] = *(const short8*)(kb + 32 + lq * 8);
            }
        }

        for (int kv0 = 0; kv0 < nkv; kv0 += 64) {
            // ---- barrier FIRST: Vt[buf] free (last readers: PV(u-2)) ----
            __syncthreads();

            // ---- write pre-staged V^T (64 kv x 64 d) into Vt[buf] ----
            {
                union { short8 v; unsigned short u[8]; } a, b;
                a.v = va; b.v = vb;
                unsigned int* vt = (unsigned int*)&Vt[buf][0];
#pragma unroll
                for (int j2 = 0; j2 < 8; j2++)
                    vt[((vd0 + j2) * VP2 + vi2) >> 1] =
                        ((unsigned int)b.u[j2] << 16) | a.u[j2];
            }

            // ---- issue next-iter global loads early (clamped on last) ----
            int kvn = (kv0 + 64 < nkv) ? kv0 + 64 : kv0;
            short8 va_n, vb_n, kf0_n[4], kf1_n[4];
            {
                const short* vs0 = base + (size_t)(kvn + vi2) * C3 + 128 + vd0;
                va_n = *(const short8*)vs0;
                vb_n = *(const short8*)(vs0 + C3);
#pragma unroll
                for (int sub = 0; sub < 4; sub++) {
                    const short* kb = base + (size_t)(kvn + sub * 16 + lrow) * C3 + 64;
                    kf0_n[sub] = *(const short8*)(kb + lq * 8);
                    kf1_n[sub] = *(const short8*)(kb + 32 + lq * 8);
                }
            }

            // ---- QK(u): S^T for both groups using pre-loaded K ----
            f32x4 s[2][4];
#pragma unroll
            for (int sub = 0; sub < 4; sub++) {
#pragma unroll
                for (int g = 0; g < 2; g++) {
                    f32x4 a = (f32x4){0.f, 0.f, 0.f, 0.f};
                    a = mfma16(kf0[sub], qf0[g], a);
                    a = mfma16(kf1[sub], qf1[g], a);
                    s[g][sub] = a;
                }
            }

            // ---- PV(u-1): Vt[buf^1] staged last iter, Pt written last iter --
            if (kv0 > 0) {
#pragma unroll
                for (int ks = 0; ks < 2; ks++) {
                    short8 pfA = *(short8*)&Pt[wave][0][lrow * PP + ks * 32 + lq * 8];
                    short8 pfB = *(short8*)&Pt[wave][1][lrow * PP + ks * 32 + lq * 8];
#pragma unroll
                    for (int nt = 0; nt < 4; nt++) {
                        short8 vf = *(short8*)&Vt[buf ^ 1][(nt * 16 + lrow) * VP2 + ks * 32 + lq * 8];
                        acc[0][nt] = mfma16(vf, pfA, acc[0][nt]);
                        acc[1][nt] = mfma16(vf, pfB, acc[1][nt]);
                    }
                }
            }

            // ---- softmax(u): mask, fixed-max exp, pack P -> Pt ----
#pragma unroll
            for (int g = 0; g < 2; g++) {
                if (causal && (kv0 + 63 > q0t + wave * 32 + g * 16)) {
#pragma unroll
                    for (int sub = 0; sub < 4; sub++) {
                        int kvg = kv0 + sub * 16 + lq * 4;
#pragma unroll
                        for (int rr = 0; rr < 4; rr++)
                            if (kvg + rr > qg[g]) s[g][sub][rr] = -1e30f;
                    }
                }
                float lsum = 0.f;
                unsigned int pk[4][2];
#pragma unroll
                for (int sub = 0; sub < 4; sub++) {
                    float p0 = __expf(s[g][sub][0] - MFIX);
                    float p1 = __expf(s[g][sub][1] - MFIX);
                    float p2 = __expf(s[g][sub][2] - MFIX);
                    float p3 = __expf(s[g][sub][3] - MFIX);
                    lsum += (p0 + p1) + (p2 + p3);
                    pk[sub][0] = cvt_pk_bf16(p0, p1);
                    pk[sub][1] = cvt_pk_bf16(p2, p3);
                }
                l_i[g] += lsum;              // per-lane; reduced in epilogue
                unsigned int* pt = (unsigned int*)&Pt[wave][g][0];
#pragma unroll
                for (int sub = 0; sub < 4; sub++)
                    *(uint2*)&pt[(lrow * PP + sub * 16 + lq * 4) >> 1] =
                        make_uint2(pk[sub][0], pk[sub][1]);
            }

            // ---- rotate prefetched registers ----
            va = va_n; vb = vb_n;
#pragma unroll
            for (int sub = 0; sub < 4; sub++) {
                kf0[sub] = kf0_n[sub];
                kf1[sub] = kf1_n[sub];
            }
            buf ^= 1;
        }

        // ---- drain: PV(last). Barrier makes ALL waves' staging of the ----
        // ---- final V-tile (in Vt[buf^1]) visible.                      ----
        __syncthreads();
#pragma unroll
        for (int ks = 0; ks < 2; ks++) {
            short8 pfA = *(short8*)&Pt[wave][0][lrow * PP + ks * 32 + lq * 8];
            short8 pfB = *(short8*)&Pt[wave][1][lrow * PP + ks * 32 + lq * 8];
#pragma unroll
            for (int nt = 0; nt < 4; nt++) {
                short8 vf = *(short8*)&Vt[buf ^ 1][(nt * 16 + lrow) * VP2 + ks * 32 + lq * 8];
                acc[0][nt] = mfma16(vf, pfA, acc[0][nt]);
                acc[1][nt] = mfma16(vf, pfB, acc[1][nt]);
            }
        }

        // ---- epilogue: reduce row-sum across lq once, normalize, pack ----
#pragma unroll
        for (int g = 0; g < 2; g++) {
            float lt = l_i[g];
            lt += __shfl_xor(lt, 16, 64);
            lt += __shfl_xor(lt, 32, 64);
            float inv = 1.f / lt;
            short* ob = AO + ((size_t)bh * S + qg[g]) * 64;
#pragma unroll
            for (int nt = 0; nt < 4; nt++) {
                float o0 = scrub(acc[g][nt][0] * inv, 4e4f);
                float o1 = scrub(acc[g][nt][1] * inv, 4e4f);
                float o2 = scrub(acc[g][nt][2] * inv, 4e4f);
                float o3 = scrub(acc[g][nt][3] * inv, 4e4f);
                *(uint2*)(ob + nt * 16 + lq * 4) =
                    make_uint2(cvt_pk_bf16(o0, o1), cvt_pk_bf16(o2, o3));
            }
        }
    }
}

// ---- launch ----
extern "C" void kernel_launch(void* const* d_in, const int* in_sizes, int n_in,
                              void* d_out, int out_size, void* d_ws, size_t ws_size,
                              hipStream_t stream) {
    char* ws = (char*)d_ws;
    int*   flag  = (int*)ws;
    short* bq_bf = (short*)(ws + 65536);
    short* bo_bf = (short*)(ws + 131072);
    short* WqkvT = (short*)(ws + (1ull << 20));
    short* WoutT = (short*)(ws + 7ull * (1ull << 20));
    short* xbfAO = (short*)(ws + 9ull * (1ull << 20));   // x_bf, later AO
    short* QKVc  = (short*)(ws + 25ull * (1ull << 20));

    detect_dtype<<<1, 256, 0, stream>>>((const unsigned short*)d_in[0], flag);

    if (ws_size < 73ull * 1048576) {
        fill_sentinel<<<(8388608 + 255) / 256, 256, 0, stream>>>(d_out, 8388608, flag);
        return;
    }

    conv_bias<<<12, 256, 0, stream>>>(d_in[2], bq_bf, 3072, flag);
    conv_bias<<<4, 256, 0, stream>>>(d_in[4], bo_bf, 1024, flag);
    transpose_poly<<<dim3(96, 32), 256, 0, stream>>>(d_in[1], WqkvT, 1024, 3072, flag);
    transpose_poly<<<dim3(32, 32), 256, 0, stream>>>(d_in[3], WoutT, 1024, 1024, flag);
    conv_x<<<8192, 256, 0, stream>>>(d_in[0], xbfAO, 8388608, flag);

    gemm_bt<<<dim3(24, 64), 256, 0, stream>>>(xbfAO, WqkvT, bq_bf, QKVc,
                                              3072, 1024, flag, 0, 8e4f);
    attn_kernel<<<dim3(8, 64), 256, 0, stream>>>(QKVc, xbfAO, (const int*)d_in[5]);
    gemm_bt<<<dim3(8, 64), 256, 0, stream>>>(xbfAO, WoutT, bo_bf, d_out,
                                             1024, 1024, flag, 1, 2e4f);
}